// Round 8
// baseline (127844.885 us; speedup 1.0000x reference)
//
#include <hip/hip_runtime.h>

// NCDE classifier: B=512 chains, T=2048 steps, D=32, M=64, W=128.
// Round-7: 64 independent blocks x 8 chains, 1 block/CU, 8 waves.
// W2: 2 pairs regs + 2 pairs LDS + 4 pairs streamed (f16 frag-linear).
// New vs r6: dxdt in per-lane regs (kills 8e8 bank conflicts); lgkm-only
// barriers (stream never drained); y/RK4 state in registers as the MFMA
// A-fragment (no YIN LDS, 3 barriers/stage).

#define TT   2048
#define NTH  512
#define NCH  8
#define R_P  2
#define L_P  2

typedef _Float16 f16;
typedef _Float16 f16x8 __attribute__((ext_vector_type(8)));
typedef float f32x4 __attribute__((ext_vector_type(4)));

// dynamic LDS layout (bytes)
#define O_W2L 0         // 32 tile-slots * 4096 = 131072 (frag-linear)
#define O_DTS 131072    // 2047 f32 (pad 8192)
#define O_B2  139264    // 2048 f32 = 8192
#define O_H1  147456    // [16][128] f16 swizzled = 4096 (enc scratch)
#define O_H2  151552    // 4096 (enc scratch)
#define O_GS  155648    // [8][64] f32 swizzled = 2048
#define O_DX  157696    // [32][8] f32 transposed = 1024 (x0 scratch pre-loop)
#define O_B0  158720    // 128 f32
#define O_B1  159232    // 128 f32
#define LDSB  159744

__device__ __forceinline__ float tanh_fast(float x){
    float e = __expf(2.0f * x);
    return 1.0f - 2.0f * __builtin_amdgcn_rcpf(e + 1.0f);
}
__device__ __forceinline__ float gelu_f(float x){
    float u = x + 0.044715f * x * x * x;
    return 0.5f * x * (1.0f + tanh_fast(0.7978845608028654f * u));
}
// LDS-only barrier: does NOT drain vmcnt -> stream loads stay in flight.
__device__ __forceinline__ void bar_lds(){
    asm volatile("s_waitcnt lgkmcnt(0)" ::: "memory");
    __builtin_amdgcn_s_barrier();
    __builtin_amdgcn_sched_barrier(0);
}

template<bool F16>
__device__ __forceinline__ void load_tile_frags(f16x8* buf, const f16* w2r,
                                                const float* vW2, int tl, int l){
    if constexpr (F16){
        const f16* base = w2r + (size_t)tl*2048 + l*8;
        #pragma unroll
        for (int kf = 0; kf < 4; ++kf)
            buf[kf] = *(const f16x8*)(base + kf*512);
    } else {
        int n = tl*16 + (l & 15);
        int k0 = (l >> 4) << 3;
        #pragma unroll
        for (int kf = 0; kf < 4; ++kf){
            const float* p = vW2 + n*128 + kf*32 + k0;
            float4 u = *(const float4*)p;
            float4 v2 = *(const float4*)(p + 4);
            f16x8 t;
            t[0]=(f16)u.x; t[1]=(f16)u.y; t[2]=(f16)u.z; t[3]=(f16)u.w;
            t[4]=(f16)v2.x; t[5]=(f16)v2.y; t[6]=(f16)v2.z; t[7]=(f16)v2.w;
            buf[kf] = t;
        }
    }
}
template<bool F16>
__device__ __forceinline__ void issue_pair(f16x8* de, f16x8* dob, const f16* w2r,
                                           const float* vW2, int w, int p, int l){
    if constexpr (F16){
        const f16* be = w2r + ((size_t)(w*16 + 2*p))*2048 + l*8;
        #pragma unroll
        for (int kf = 0; kf < 4; ++kf){
            de[kf]  = *(const f16x8*)(be + kf*512);
            dob[kf] = *(const f16x8*)(be + 2048 + kf*512);
        }
    } else {
        load_tile_frags<false>(de,  nullptr, vW2, w*16 + 2*p,     l);
        load_tile_frags<false>(dob, nullptr, vW2, w*16 + 2*p + 1, l);
    }
}

// Pre-pass: W2 f32 [2048][128] -> frag-linear f16: idx = ((tl*4+kf)*64+l)*8+i
__global__ void __launch_bounds__(512) reorder_w2(const float* __restrict__ vW2,
                                                  f16* __restrict__ w2r){
    int idx = blockIdx.x * 512 + threadIdx.x;
    int i  = idx & 7;
    int l  = (idx >> 3) & 63;
    int kf = (idx >> 9) & 3;
    int tl = idx >> 11;
    int n = tl*16 + (l & 15);
    int k = kf*32 + ((l >> 4) << 3) + i;
    w2r[idx] = (f16)vW2[n*128 + k];
}

template<bool F16>
__global__ void __launch_bounds__(NTH, 1)
ncde_main(const float* __restrict__ times, const float* __restrict__ xs,
          const float* __restrict__ eW0, const float* __restrict__ eb0,
          const float* __restrict__ eW1, const float* __restrict__ eb1,
          const float* __restrict__ eW2, const float* __restrict__ eb2,
          const float* __restrict__ vW0, const float* __restrict__ vW1,
          const float* __restrict__ vb0, const float* __restrict__ vb1,
          const float* __restrict__ vW2, const float* __restrict__ vb2,
          const float* __restrict__ dW, const float* __restrict__ db,
          const f16* __restrict__ w2r, float* __restrict__ out)
{
    extern __shared__ __align__(16) char lds[];
    float* dtsf = (float*)(lds + O_DTS);
    float* gsf  = (float*)(lds + O_GS);
    float* dxf  = (float*)(lds + O_DX);
    float* b2s  = (float*)(lds + O_B2);
    float* b0f  = (float*)(lds + O_B0);
    float* b1f  = (float*)(lds + O_B1);
    float* enc1f= (float*)(lds + O_H1);
    float* enc2f= (float*)(lds + O_H2);

    const int tid = threadIdx.x;
    const int l   = tid & 63;
    const int w   = tid >> 6;
    const int c0  = blockIdx.x * NCH;

    for (int i = tid; i < 2047; i += NTH) dtsf[i] = times[i+1] - times[i];
    for (int i = tid; i < 2048; i += NTH) b2s[i] = vb2[i];
    if (tid < 128){ b0f[tid] = vb0[tid]; b1f[tid] = vb1[tid]; }

    float xcur = 0.f, xn = 0.f;
    if (tid < 256){
        int r = tid >> 5, d = tid & 31;
        xcur = xs[((size_t)(c0 + r) * TT + 0) * 32 + d];
        xn   = xs[((size_t)(c0 + r) * TT + 1) * 32 + d];
        dxf[r*32 + d] = xcur;            // x0 scratch (plain layout, pre-loop)
    }
    __syncthreads();

    // ---- encoder ----
    for (int i = tid; i < NCH*128; i += NTH){
        int r = i >> 7, n = i & 127;
        float a = eb0[n];
        #pragma unroll
        for (int k = 0; k < 32; ++k) a += eW0[n*32 + k] * dxf[r*32 + k];
        enc1f[i] = fmaxf(a, 0.f);
    }
    __syncthreads();
    for (int i = tid; i < NCH*128; i += NTH){
        int r = i >> 7, n = i & 127;
        float a = eb1[n];
        for (int k = 0; k < 128; ++k) a += eW1[n*128 + k] * enc1f[r*128 + k];
        enc2f[i] = fmaxf(a, 0.f);
    }
    __syncthreads();
    float y0;
    {
        int r = tid >> 6, m = tid & 63;
        float a = eb2[m];
        for (int k = 0; k < 128; ++k) a += eW2[m*128 + k] * enc2f[r*128 + k];
        y0 = a;
    }
    __syncthreads();

    // zero H1/H2 (rows 8-15 stay zero); seed gsf with y0 (swizzled)
    for (int i = tid; i < 8192/4; i += NTH)
        ((unsigned*)(lds + O_H1))[i] = 0u;
    {
        int r = tid >> 6, m = tid & 63;
        gsf[r*64 + (m ^ (r << 3))] = y0;
    }
    __syncthreads();

    const int g    = l >> 4;            // 16-lane group
    const int arow = l & 15;
    const int ridx = l & 7;             // mirrored chain row
    const int c    = l & 15;

    // ---- y state in registers (A-fragment layout) ----
    float y_r[16], ka_r[16];
    f16x8 ah[2];
    #pragma unroll
    for (int kf = 0; kf < 2; ++kf){
        int off = O_GS + ridx*256 + ((((kf<<2)+g) ^ ridx) << 5);
        f32x4 a = *(const f32x4*)(lds + off);
        f32x4 b = *(const f32x4*)(lds + off + 16);
        #pragma unroll
        for (int i = 0; i < 4; ++i){ y_r[kf*8+i] = a[i]; y_r[kf*8+4+i] = b[i]; }
        f16x8 h;
        #pragma unroll
        for (int i = 0; i < 8; ++i) h[i] = (f16)y_r[kf*8+i];
        ah[kf] = h;
    }

    // ---- LDS-resident W2 (frag-linear) ----
    if constexpr (F16){
        for (int i = tid; i < 8192; i += NTH){
            int slot = i >> 8, b = (i & 255) << 4;
            int sw = slot >> 2, sp = (slot >> 1) & 1, se = slot & 1;
            int tl = sw*16 + 2*(R_P + sp) + se;
            *(f16x8*)(lds + O_W2L + slot*4096 + b) =
                *(const f16x8*)((const char*)w2r + (size_t)tl*4096 + b);
        }
    } else {
        for (int i = tid; i < 65536; i += NTH){
            int slot = i >> 11, elem = i & 2047;
            int sw = slot >> 2, sp = (slot >> 1) & 1, se = slot & 1;
            int tl = sw*16 + 2*(R_P + sp) + se;
            int kf = elem >> 9, rem = elem & 511, ll = rem >> 3, ii = rem & 7;
            int n = tl*16 + (ll & 15);
            int k = kf*32 + ((ll >> 4) << 3) + ii;
            *(f16*)(lds + O_W2L + slot*4096 + elem*2) = (f16)vW2[n*128 + k];
        }
    }

    // ---- W0/W1 + register W2 pairs ----
    f16x8 w0f[2], w1f[4];
    {
        int col  = w*16 + c;
        int krow = g << 3;
        #pragma unroll
        for (int ks = 0; ks < 2; ++ks){
            const float* p = vW0 + col*64 + ks*32 + krow;
            f16x8 v;
            #pragma unroll
            for (int i = 0; i < 8; ++i) v[i] = (f16)p[i];
            w0f[ks] = v;
        }
        #pragma unroll
        for (int ks = 0; ks < 4; ++ks){
            const float* p = vW1 + col*128 + ks*32 + krow;
            f16x8 v;
            #pragma unroll
            for (int i = 0; i < 8; ++i) v[i] = (f16)p[i];
            w1f[ks] = v;
        }
    }
    f16x8 rw2[R_P][2][4];
    #pragma unroll
    for (int p = 0; p < R_P; ++p)
        #pragma unroll
        for (int e = 0; e < 2; ++e)
            load_tile_frags<F16>(rw2[p][e], w2r, vW2, w*16 + 2*p + e, l);
    __syncthreads();

    for (int t = 0; t < TT-1; ++t){
        float dtv = dtsf[t];
        float xf = 0.f;
        if (tid < 256){
            int r = tid >> 5, d = tid & 31;
            if (t + 2 < TT) xf = xs[((size_t)(c0 + r) * TT + (t+2)) * 32 + d];
            dxf[d*8 + r] = (xn - xcur) / dtv;   // transposed [32][8]
            xcur = xn;
        }
        #pragma unroll
        for (int i = 0; i < 16; ++i) ka_r[i] = 0.f;
        bar_lds();
        // hoist dxdt into regs (once per t)
        float dxe[4], dxd[4];
        {
            int rowblk4 = (g & 1) << 4;        // byte offset of row block
            f32x4 v0 = *(const f32x4*)(lds + O_DX + c*32 + rowblk4);
            f32x4 v1 = *(const f32x4*)(lds + O_DX + (c+16)*32 + rowblk4);
            #pragma unroll
            for (int j = 0; j < 4; ++j){ dxe[j] = v0[j]; dxd[j] = v1[j]; }
        }

        #pragma unroll 1
        for (int st = 0; st < 4; ++st){
            f16x8 sAe[4], sAo[4], sBe[4], sBo[4];
            issue_pair<F16>(sAe, sAo, w2r, vW2, w, 4, l);
            issue_pair<F16>(sBe, sBo, w2r, vW2, w, 5, l);

            // ---- L1 ----
            {
                f32x4 acc = {0.f,0.f,0.f,0.f};
                #pragma unroll
                for (int kf = 0; kf < 2; ++kf)
                    acc = __builtin_amdgcn_mfma_f32_16x16x32_f16(ah[kf], w0f[kf], acc, 0, 0, 0);
                if (g < 2){
                    int col = w*16 + c;
                    float bb = b0f[col];
                    #pragma unroll
                    for (int j = 0; j < 4; ++j){
                        int row = g*4 + j;
                        float gg = gelu_f(acc[j] + bb);
                        *(f16*)(lds + O_H1 + row*256 + ((col*2) ^ ((row & 7) << 4))) = (f16)gg;
                    }
                }
            }
            bar_lds();
            // ---- L2 ----
            {
                f32x4 acc = {0.f,0.f,0.f,0.f};
                #pragma unroll
                for (int kf = 0; kf < 4; ++kf){
                    f16x8 a = *(const f16x8*)(lds + O_H1 + arow*256 +
                               ((kf*64 + g*16) ^ ((arow & 7) << 4)));
                    acc = __builtin_amdgcn_mfma_f32_16x16x32_f16(a, w1f[kf], acc, 0, 0, 0);
                }
                if (g < 2){
                    int col = w*16 + c;
                    float bb = b1f[col];
                    #pragma unroll
                    for (int j = 0; j < 4; ++j){
                        int row = g*4 + j;
                        float gg = gelu_f(acc[j] + bb);
                        *(f16*)(lds + O_H2 + row*256 + ((col*2) ^ ((row & 7) << 4))) = (f16)gg;
                    }
                }
            }
            bar_lds();
            // ---- L3 ----
            {
                f16x8 a3[4];
                #pragma unroll
                for (int kf = 0; kf < 4; ++kf)
                    a3[kf] = *(const f16x8*)(lds + O_H2 + arow*256 +
                              ((kf*64 + g*16) ^ ((arow & 7) << 4)));

                #pragma unroll
                for (int p = 0; p < 8; ++p){
                    f16x8 fe[4], fo[4];
                    if (p < R_P){
                        #pragma unroll
                        for (int kf = 0; kf < 4; ++kf){ fe[kf] = rw2[p][0][kf]; fo[kf] = rw2[p][1][kf]; }
                    } else if (p < R_P + L_P){
                        int slotb = O_W2L + (w*4 + (p - R_P)*2) * 4096 + l*16;
                        #pragma unroll
                        for (int kf = 0; kf < 4; ++kf){
                            fe[kf] = *(const f16x8*)(lds + slotb + kf*1024);
                            fo[kf] = *(const f16x8*)(lds + slotb + 4096 + kf*1024);
                        }
                    } else if (p == 4 || p == 6){
                        #pragma unroll
                        for (int kf = 0; kf < 4; ++kf){ fe[kf] = sAe[kf]; fo[kf] = sAo[kf]; }
                    } else {
                        #pragma unroll
                        for (int kf = 0; kf < 4; ++kf){ fe[kf] = sBe[kf]; fo[kf] = sBo[kf]; }
                    }
                    f32x4 ae = {0.f,0.f,0.f,0.f}, ao = {0.f,0.f,0.f,0.f};
                    #pragma unroll
                    for (int kf = 0; kf < 4; ++kf){
                        ae = __builtin_amdgcn_mfma_f32_16x16x32_f16(a3[kf], fe[kf], ae, 0, 0, 0);
                        ao = __builtin_amdgcn_mfma_f32_16x16x32_f16(a3[kf], fo[kf], ao, 0, 0, 0);
                    }
                    if (p == 4) issue_pair<F16>(sAe, sAo, w2r, vW2, w, 6, l);
                    if (p == 5) issue_pair<F16>(sBe, sBo, w2r, vW2, w, 7, l);
                    {
                        float be = b2s[(w*16 + 2*p)*16 + c];
                        float bo = b2s[(w*16 + 2*p + 1)*16 + c];
                        #pragma unroll
                        for (int j = 0; j < 4; ++j){
                            float pe = tanh_fast(ae[j] + be) * dxe[j]
                                     + tanh_fast(ao[j] + bo) * dxd[j];
                            pe += __shfl_xor(pe, 1);
                            pe += __shfl_xor(pe, 2);
                            pe += __shfl_xor(pe, 4);
                            pe += __shfl_xor(pe, 8);
                            if (g < 2 && c == p){
                                int rr = g*4 + j;
                                gsf[rr*64 + ((w*8 + p) ^ (rr << 3))] = pe;
                            }
                        }
                    }
                }
            }
            bar_lds();
            // ---- RK4 update in registers (A-frag for next stage) ----
            {
                float kv[16];
                #pragma unroll
                for (int kf = 0; kf < 2; ++kf){
                    int off = O_GS + ridx*256 + ((((kf<<2)+g) ^ ridx) << 5);
                    f32x4 a = *(const f32x4*)(lds + off);
                    f32x4 b = *(const f32x4*)(lds + off + 16);
                    #pragma unroll
                    for (int i = 0; i < 4; ++i){ kv[kf*8+i] = a[i]; kv[kf*8+4+i] = b[i]; }
                }
                float wgt = (st == 1 || st == 2) ? 2.f : 1.f;
                float ys[16];
                #pragma unroll
                for (int i = 0; i < 16; ++i) ka_r[i] += wgt * kv[i];
                if (st < 3){
                    float cs = (st == 2) ? dtv : 0.5f*dtv;
                    #pragma unroll
                    for (int i = 0; i < 16; ++i) ys[i] = y_r[i] + cs * kv[i];
                } else {
                    #pragma unroll
                    for (int i = 0; i < 16; ++i){ y_r[i] += (dtv*(1.0f/6.0f)) * ka_r[i]; ys[i] = y_r[i]; }
                }
                #pragma unroll
                for (int kf = 0; kf < 2; ++kf){
                    f16x8 h;
                    #pragma unroll
                    for (int i = 0; i < 8; ++i) h[i] = (f16)ys[kf*8+i];
                    ah[kf] = h;
                }
            }
        } // stages
        if (tid < 256) xn = xf;
    } // t

    // ---- decoder ----
    __syncthreads();
    if (arow < 8){
        #pragma unroll
        for (int kf = 0; kf < 2; ++kf){
            f32x4 a, b;
            #pragma unroll
            for (int i = 0; i < 4; ++i){ a[i] = y_r[kf*8+i]; b[i] = y_r[kf*8+4+i]; }
            *(f32x4*)(&gsf[arow*64 + kf*32 + g*8])     = a;
            *(f32x4*)(&gsf[arow*64 + kf*32 + g*8 + 4]) = b;
        }
    }
    __syncthreads();
    if (tid < NCH){
        float a = db[0];
        for (int m = 0; m < 64; ++m) a += gsf[tid*64 + m] * dW[m];
        out[c0 + tid] = 1.0f / (1.0f + __expf(-a));
    }
}

extern "C" void kernel_launch(void* const* d_in, const int* in_sizes, int n_in,
                              void* d_out, int out_size, void* d_ws, size_t ws_size,
                              hipStream_t stream)
{
    const float* times = (const float*)d_in[0];
    const float* xs    = (const float*)d_in[1];
    const float* eW0   = (const float*)d_in[2];
    const float* eb0   = (const float*)d_in[3];
    const float* eW1   = (const float*)d_in[4];
    const float* eb1   = (const float*)d_in[5];
    const float* eW2   = (const float*)d_in[6];
    const float* eb2   = (const float*)d_in[7];
    const float* vW0   = (const float*)d_in[8];
    const float* vb0   = (const float*)d_in[9];
    const float* vW1   = (const float*)d_in[10];
    const float* vb1   = (const float*)d_in[11];
    const float* vW2   = (const float*)d_in[12];
    const float* vb2   = (const float*)d_in[13];
    const float* dW    = (const float*)d_in[14];
    const float* db    = (const float*)d_in[15];

    const size_t w2_bytes = (size_t)2048 * 128 * sizeof(f16);   // 512 KB
    if (ws_size >= w2_bytes){
        f16* w2r = (f16*)d_ws;
        reorder_w2<<<dim3(512), dim3(512), 0, stream>>>(vW2, w2r);
        hipFuncSetAttribute((const void*)ncde_main<true>,
                            hipFuncAttributeMaxDynamicSharedMemorySize, LDSB);
        ncde_main<true><<<dim3(64), dim3(NTH), LDSB, stream>>>(
            times, xs, eW0, eb0, eW1, eb1, eW2, eb2,
            vW0, vW1, vb0, vb1, vW2, vb2, dW, db,
            (const f16*)w2r, (float*)d_out);
    } else {
        hipFuncSetAttribute((const void*)ncde_main<false>,
                            hipFuncAttributeMaxDynamicSharedMemorySize, LDSB);
        ncde_main<false><<<dim3(64), dim3(NTH), LDSB, stream>>>(
            times, xs, eW0, eb0, eW1, eb1, eW2, eb2,
            vW0, vW1, vb0, vb1, vW2, vb2, dW, db,
            (const f16*)nullptr, (float*)d_out);
    }
}